// Round 6
// baseline (31.707 us; speedup 1.0000x reference)
//
#include <hip/hip_runtime.h>
#include <math.h>

#define NB 16
#define NQ 900
#define NQP 912             // padded teacher count (57*16)
#define NC 80
#define EPSV 1e-7f
#define IOU_THR 0.1f
#define SPB 32              // students per block (2 per thread-group)
#define CHB 29              // blocks per batch (29*32 = 928 >= 900)

__device__ __forceinline__ float sigm(float x) { return 1.0f / (1.0f + __expf(-x)); }

// ---- K1: per-(b, 32 students): register-tiled IoU argmax + cnt scatter + BCE/conf ----
__global__ __launch_bounds__(256) void k_main(
    const float* __restrict__ s_logits,
    const float* __restrict__ s_boxes,
    const float* __restrict__ t_logits,
    const float* __restrict__ t_boxes,
    int*    __restrict__ g_cnt,     // [NB*NQ]  zeroed by memset node; cnt[b,j] += 1
    float*  __restrict__ g_v,       // [NB*NQ]  flag-gated 5*l1+2*(1-giou), else 0
    float2* __restrict__ g_part)    // [NB*CHB] (bce_sum, conf_any)
{
    __shared__ float4 tcor[NQP];    // x1, x2, y1, y2 (padded tail: impossible boxes)
    __shared__ int    lidx[SPB];
    __shared__ float  sconf0;
    __shared__ float2 sres[SPB];    // per-row (bce_mean, conf)

    const int bx  = blockIdx.x;     // 0..28
    const int b   = blockIdx.y;     // 0..15
    const int tid = threadIdx.x;

    // stage teacher corners of batch b (padded)
    const float4* tb = (const float4*)(t_boxes + b * NQ * 4);
    for (int i = tid; i < NQP; i += 256) {
        if (i < NQ) {
            float4 t = tb[i];
            float hw = t.z * 0.5f, hh = t.w * 0.5f;
            tcor[i] = make_float4(t.x - hw, t.x + hw, t.y - hh, t.y + hh);
        } else {
            tcor[i] = make_float4(2e9f, -2e9f, 2e9f, -2e9f);  // inter == 0 exactly
        }
    }
    // conf0[b] (one wave; redundant per block but cheap)
    if (tid < 64) {
        const float* tl = t_logits + b * NQ * NC;   // teacher row 0 of batch b
        float m = tl[tid];
        if (tid < NC - 64) m = fmaxf(m, tl[tid + 64]);
        for (int s = 32; s >= 1; s >>= 1) m = fmaxf(m, __shfl_xor(m, s, 64));
        if (tid == 0) sconf0 = (sigm(m) > 0.2f) ? 1.0f : 0.0f;
    }
    __syncthreads();

    // ---- argmax IoU: 16 lanes x 2 students per lane-group ----
    const int g   = tid >> 4;       // 0..15 group
    const int tc  = tid & 15;       // teacher phase
    const int sq0 = bx * SPB + g * 2;
    const int sq1 = sq0 + 1;
    const bool a0 = (sq0 < NQ), a1 = (sq1 < NQ);

    float4 sb0 = make_float4(0.f,0.f,0.f,0.f), sb1 = sb0;
    if (a0) sb0 = ((const float4*)(s_boxes + b * NQ * 4))[sq0];
    if (a1) sb1 = ((const float4*)(s_boxes + b * NQ * 4))[sq1];
    const float s0x1 = sb0.x - sb0.z*0.5f, s0x2 = sb0.x + sb0.z*0.5f;
    const float s0y1 = sb0.y - sb0.w*0.5f, s0y2 = sb0.y + sb0.w*0.5f;
    const float s0a  = sb0.z * sb0.w;
    const float s1x1 = sb1.x - sb1.z*0.5f, s1x2 = sb1.x + sb1.z*0.5f;
    const float s1y1 = sb1.y - sb1.w*0.5f, s1y2 = sb1.y + sb1.w*0.5f;
    const float s1a  = sb1.z * sb1.w;

    float best0 = -1.0f, best1 = -1.0f; int bi0 = 0, bi1 = 0;
    #pragma unroll 4
    for (int i = 0; i < 57; ++i) {
        int t = tc + (i << 4);
        float4 c = tcor[t];
        float ta = (c.y - c.x) * (c.w - c.z);   // recompute area (saves LDS read)
        float iw0 = fminf(s0x2, c.y) - fmaxf(s0x1, c.x);
        float ih0 = fminf(s0y2, c.w) - fmaxf(s0y1, c.z);
        float in0 = fmaxf(iw0, 0.0f) * fmaxf(ih0, 0.0f);
        float io0 = in0 * __frcp_rn(s0a + ta - in0 + EPSV);
        if (io0 > best0) { best0 = io0; bi0 = t; }
        float iw1 = fminf(s1x2, c.y) - fmaxf(s1x1, c.x);
        float ih1 = fminf(s1y2, c.w) - fmaxf(s1y1, c.z);
        float in1 = fmaxf(iw1, 0.0f) * fmaxf(ih1, 0.0f);
        float io1 = in1 * __frcp_rn(s1a + ta - in1 + EPSV);
        if (io1 > best1) { best1 = io1; bi1 = t; }
    }
    // combine 16 phases (within 16-lane groups); ties -> lower teacher index
    for (int m = 1; m <= 8; m <<= 1) {
        float ov0 = __shfl_xor(best0, m, 64); int oi0 = __shfl_xor(bi0, m, 64);
        if (ov0 > best0 || (ov0 == best0 && oi0 < bi0)) { best0 = ov0; bi0 = oi0; }
        float ov1 = __shfl_xor(best1, m, 64); int oi1 = __shfl_xor(bi1, m, 64);
        if (ov1 > best1 || (ov1 == best1 && oi1 < bi1)) { best1 = ov1; bi1 = oi1; }
    }
    if (tc == 0) {
        float4 t0 = tb[0];
        float4 c  = tcor[0];
        #pragma unroll
        for (int k = 0; k < 2; ++k) {
            const bool  ak = k ? a1 : a0;
            if (!ak) continue;
            const int   sq = k ? sq1 : sq0;
            const float best = k ? best1 : best0;
            const int   bi   = k ? bi1 : bi0;
            const float4 sb  = k ? sb1 : sb0;
            const float sx1 = k ? s1x1 : s0x1, sx2 = k ? s1x2 : s0x2;
            const float sy1 = k ? s1y1 : s0y1, sy2 = k ? s1y2 : s0y2;
            const float sa  = k ? s1a : s0a;
            int o = b * NQ + sq;
            lidx[g * 2 + k] = bi;
            atomicAdd(&g_cnt[b * NQ + bi], 1);
            // L1 and (1 - GIoU) vs teacher box 0 (exact divides like ref)
            float iw = fminf(sx2, c.y) - fmaxf(sx1, c.x);
            float ih = fminf(sy2, c.w) - fmaxf(sy1, c.z);
            float inter = fmaxf(iw, 0.0f) * fmaxf(ih, 0.0f);
            float uni = sa + t0.z * t0.w - inter + EPSV;
            float iou = inter / uni;
            float cw = fmaxf(sx2, c.y) - fminf(sx1, c.x);
            float ch = fmaxf(sy2, c.w) - fminf(sy1, c.z);
            float carea = cw * ch + EPSV;
            float giou1 = 1.0f - (iou - (carea - uni) / carea);
            float l1 = fabsf(sb.x - t0.x) + fabsf(sb.y - t0.y) +
                       fabsf(sb.z - t0.z) + fabsf(sb.w - t0.w);
            float v = 0.0f;
            if (sconf0 > 0.0f && best > IOU_THR) v = 5.0f * l1 + 2.0f * giou1;
            g_v[o] = v;
        }
    }
    __syncthreads();

    // ---- BCE + conf: 16-lane group per row, 16 rows/pass, 2 passes ----
    const int wv  = tid >> 6, lane = tid & 63;
    const int grp = lane >> 4, tc2 = lane & 15;
    #pragma unroll
    for (int pass = 0; pass < 2; ++pass) {
        const int r   = pass * 16 + wv * 4 + grp;    // 0..31
        const int sq2 = bx * SPB + r;
        if (sq2 < NQ) {
            int row = b * NQ + sq2;
            int j   = lidx[r];                 // flat idx -> batch-0 teacher row (ref quirk)
            const float* srow = s_logits + row * NC;
            const float* trow = t_logits + row * NC;
            const float* grow = t_logits + j * NC;
            float bce = 0.f, tmax = -1e30f;
            #pragma unroll
            for (int e = 0; e < 5; ++e) {
                int cc = e * 16 + tc2;
                float s0 = srow[cc], t0 = trow[cc], g0 = grow[cc];
                bce += fmaxf(s0, 0.f) + __logf(1.0f + __expf(-fabsf(s0)))
                     - s0 * __frcp_rn(1.0f + __expf(-g0));
                tmax = fmaxf(tmax, t0);
            }
            for (int m = 8; m >= 1; m >>= 1) {
                bce  += __shfl_xor(bce, m, 64);
                tmax  = fmaxf(tmax, __shfl_xor(tmax, m, 64));
            }
            if (tc2 == 0)
                sres[r] = make_float2(bce * (1.0f / (float)NC),
                                      (sigm(tmax) > 0.2f) ? 1.0f : 0.0f);
        }
    }
    __syncthreads();
    if (tid < 64) {
        float bs = 0.f, ca = 0.f;
        if (tid < SPB) { float2 p = sres[tid]; bs = p.x; ca = p.y; }
        for (int m = 32; m >= 1; m >>= 1) {
            bs += __shfl_xor(bs, m, 64);
            ca  = fmaxf(ca, __shfl_xor(ca, m, 64));
        }
        if (tid == 0) g_part[b * CHB + bx] = make_float2(bs, ca);
    }
}

// ---- K2: single block — coalesced cnt·v dot + partial reduce + finalize ----
__global__ __launch_bounds__(1024) void k_final(
    const int*    __restrict__ g_cnt,
    const float*  __restrict__ g_v,
    const float2* __restrict__ g_part,
    const int*    __restrict__ tn_p,
    float* __restrict__ out)
{
    const int tid = threadIdx.x;
    float bs = 0.f, ca = 0.f;
    if (tid < NB * CHB) { float2 p = g_part[tid]; bs = p.x; ca = p.y; }
    float vs = 0.f;
    #pragma unroll
    for (int k = 0; k < 15; ++k) {
        int i = tid + k * 1024;
        if (i < NB * NQ) vs += (float)g_cnt[i] * g_v[i];   // coalesced, no indirection
    }
    __shared__ float rb[16], rv[16], rc[16];
    const int wv = tid >> 6, lane = tid & 63;
    for (int m = 32; m >= 1; m >>= 1) {
        bs += __shfl_xor(bs, m, 64);
        vs += __shfl_xor(vs, m, 64);
        ca  = fmaxf(ca, __shfl_xor(ca, m, 64));
    }
    if (lane == 0) { rb[wv] = bs; rv[wv] = vs; rc[wv] = ca; }
    __syncthreads();
    if (tid == 0) {
        float sb = 0.f, sv = 0.f, sc = 0.f;
        for (int k = 0; k < 16; ++k) { sb += rb[k]; sv += rv[k]; sc = fmaxf(sc, rc[k]); }
        float tn = (float)tn_p[0];
        out[0] = (sc > 0.f) ? (sv + sb) / tn : 0.0f;
    }
}

extern "C" void kernel_launch(void* const* d_in, const int* in_sizes, int n_in,
                              void* d_out, int out_size, void* d_ws, size_t ws_size,
                              hipStream_t stream) {
    const float* s_logits = (const float*)d_in[0];
    const float* s_boxes  = (const float*)d_in[1];
    const float* t_logits = (const float*)d_in[2];
    const float* t_boxes  = (const float*)d_in[3];
    const int*   tn       = (const int*)d_in[4];
    float* out = (float*)d_out;

    char* ws = (char*)d_ws;
    int*    g_cnt  = (int*)(ws);              // 14400 i32 @ 0 (zeroed per call)
    float*  g_v    = (float*)(ws + 57600);    // 14400 f32
    float2* g_part = (float2*)(ws + 115200);  // 464 float2

    hipMemsetAsync(g_cnt, 0, NB * NQ * sizeof(int), stream);
    k_main<<<dim3(CHB, NB), 256, 0, stream>>>(s_logits, s_boxes, t_logits, t_boxes,
                                              g_cnt, g_v, g_part);
    k_final<<<1, 1024, 0, stream>>>(g_cnt, g_v, g_part, tn, out);
}